// Round 1
// baseline (337.852 us; speedup 1.0000x reference)
//
#include <hip/hip_runtime.h>

using u16 = unsigned short;
using u32 = unsigned int;
typedef __bf16 bf16x8 __attribute__((ext_vector_type(8)));
typedef u16 u16x8 __attribute__((ext_vector_type(8)));
typedef float f32x4 __attribute__((ext_vector_type(4)));

#define B_   2
#define S_   2048
#define DIN  1024
#define HID  1024
#define NH   16
#define NKV  4
#define HD_  64
#define SCALE_ 0.125f

__device__ __forceinline__ u16 f2b(float f) {
  u32 u = __builtin_bit_cast(u32, f);
  u32 r = (u + 0x7FFFu + ((u >> 16) & 1u)) >> 16;
  return (u16)r;
}

// ---------------- converters ----------------
__global__ void k_cvt(const float* __restrict__ in, u16* __restrict__ out, int n) {
  int i = blockIdx.x * 256 + threadIdx.x;
  if (i < n) out[i] = f2b(in[i]);
}

// W is K x N row-major (in,out). WT[n][k] = bf16(W[k][n]).  Requires K%32==0, N%8==0.
__global__ void k_cvt_t(const float* __restrict__ W, u16* __restrict__ WT, int K, int N) {
  int k = blockIdx.x * 32 + (threadIdx.x & 31);
  int n = blockIdx.y * 8 + (threadIdx.x >> 5);
  WT[(size_t)n * K + k] = f2b(W[(size_t)k * N + n]);
}

// ---------------- GEMM: C = A * Bt^T ----------------
// A: M x K row-major bf16. Bt: N x K row-major bf16. C: M x N row-major (float or bf16).
// Requires M%128==0, N%128==0, K%32==0. 256 threads = 4 waves in 2x2; each wave 64x64.
template <typename OutT>
__global__ __launch_bounds__(256) void k_gemm_bt(
    const u16* __restrict__ A, const u16* __restrict__ Bt,
    OutT* __restrict__ C, int M, int N, int K)
{
  constexpr int LD = 40;  // padded row (u16) -> 80B stride, 16B-aligned, 2-way banks (free)
  __shared__ u16 lA[128 * LD];
  __shared__ u16 lB[128 * LD];
  const int tid  = threadIdx.x;
  const int lane = tid & 63;
  const int wave = tid >> 6;
  const int wm = wave >> 1, wn = wave & 1;
  const int g = lane >> 4, li = lane & 15;
  const int bm = blockIdx.y * 128, bn = blockIdx.x * 128;
  const int srow = tid >> 2, scol = (tid & 3) * 8;

  f32x4 acc[4][4];
#pragma unroll
  for (int i = 0; i < 4; ++i)
#pragma unroll
    for (int j = 0; j < 4; ++j) acc[i][j] = f32x4{0.f, 0.f, 0.f, 0.f};

  const u16* Ab = A + (size_t)bm * K;
  const u16* Bb = Bt + (size_t)bn * K;

  for (int k0 = 0; k0 < K; k0 += 32) {
    __syncthreads();  // previous iteration's reads done before overwrite
#pragma unroll
    for (int h = 0; h < 2; ++h) {
      u16x8 av = *(const u16x8*)&Ab[(size_t)(h * 64 + srow) * K + k0 + scol];
      u16x8 bv = *(const u16x8*)&Bb[(size_t)(h * 64 + srow) * K + k0 + scol];
      *(u16x8*)&lA[(h * 64 + srow) * LD + scol] = av;
      *(u16x8*)&lB[(h * 64 + srow) * LD + scol] = bv;
    }
    __syncthreads();
    bf16x8 af[4], bfr[4];
#pragma unroll
    for (int mt = 0; mt < 4; ++mt)
      af[mt] = *(const bf16x8*)&lA[(wm * 64 + mt * 16 + li) * LD + g * 8];
#pragma unroll
    for (int nt = 0; nt < 4; ++nt)
      bfr[nt] = *(const bf16x8*)&lB[(wn * 64 + nt * 16 + li) * LD + g * 8];
#pragma unroll
    for (int mt = 0; mt < 4; ++mt)
#pragma unroll
      for (int nt = 0; nt < 4; ++nt)
        acc[mt][nt] = __builtin_amdgcn_mfma_f32_16x16x32_bf16(af[mt], bfr[nt], acc[mt][nt], 0, 0, 0);
  }

#pragma unroll
  for (int mt = 0; mt < 4; ++mt)
#pragma unroll
    for (int nt = 0; nt < 4; ++nt)
#pragma unroll
      for (int r = 0; r < 4; ++r) {
        int row = bm + wm * 64 + mt * 16 + g * 4 + r;
        int col = bn + wn * 64 + nt * 16 + li;
        float v = acc[mt][nt][r];
        if constexpr (sizeof(OutT) == 4) C[(size_t)row * N + col] = v;
        else                             C[(size_t)row * N + col] = f2b(v);
      }
}

// ---------------- flash attention ----------------
// Q: (B,S,H,HD) bf16.  K,V: (B,S,HKV,HD) bf16.  O: (B,S,H,HD) bf16.
// 1 wave per block; block = 16 Q rows of one head. grid (S/16, H, B).
__global__ __launch_bounds__(64) void k_attn(
    const u16* __restrict__ Q, const u16* __restrict__ Kc,
    const u16* __restrict__ Vc, u16* __restrict__ O)
{
  __shared__ u16 P_lds[16 * 40];
  __shared__ u16 Vt_lds[64 * 40];
  const int lane = threadIdx.x;
  const int g = lane >> 4, li = lane & 15;
  const int s0 = blockIdx.x * 16;
  const int h  = blockIdx.y;
  const int b  = blockIdx.z;
  const int kv = h >> 2;

  // Q fragments: row s = s0+li, k-dim d = kk*32 + g*8 + j
  bf16x8 qf[2];
  {
    const u16* qb = Q + ((size_t)(b * S_ + s0 + li) * HID) + h * HD_ + g * 8;
    qf[0] = *(const bf16x8*)(qb);
    qf[1] = *(const bf16x8*)(qb + 32);
  }

  float m[4], l[4];
  f32x4 oacc[4];
#pragma unroll
  for (int r = 0; r < 4; ++r) { m[r] = -1e30f; l[r] = 0.f; }
#pragma unroll
  for (int nt = 0; nt < 4; ++nt) oacc[nt] = f32x4{0.f, 0.f, 0.f, 0.f};

  for (int t0 = 0; t0 < S_; t0 += 32) {
    // QK^T for 32 keys -> st[tc] covers cols tc*16+li, rows g*4+r
    f32x4 st[2];
#pragma unroll
    for (int tc = 0; tc < 2; ++tc) {
      st[tc] = f32x4{0.f, 0.f, 0.f, 0.f};
      const u16* kb = Kc + (size_t)(b * S_ + t0 + tc * 16 + li) * (NKV * HD_) + kv * HD_ + g * 8;
      bf16x8 kf0 = *(const bf16x8*)(kb);
      bf16x8 kf1 = *(const bf16x8*)(kb + 32);
      st[tc] = __builtin_amdgcn_mfma_f32_16x16x32_bf16(qf[0], kf0, st[tc], 0, 0, 0);
      st[tc] = __builtin_amdgcn_mfma_f32_16x16x32_bf16(qf[1], kf1, st[tc], 0, 0, 0);
    }

    // stage V tile transposed: Vt_lds[d][t_local]
    {
      const int tl = lane >> 1, dh = (lane & 1) * 32;
      const u16* vb = Vc + (size_t)(b * S_ + t0 + tl) * (NKV * HD_) + kv * HD_ + dh;
#pragma unroll
      for (int j = 0; j < 4; ++j) {
        u16x8 v = *(const u16x8*)(vb + j * 8);
#pragma unroll
        for (int e = 0; e < 8; ++e) Vt_lds[(dh + j * 8 + e) * 40 + tl] = v[e];
      }
    }

    // online softmax (per r: one of this group's 4 rows)
    float p0[4], p1[4];
#pragma unroll
    for (int r = 0; r < 4; ++r) {
      float s0v = st[0][r] * SCALE_;
      float s1v = st[1][r] * SCALE_;
      float tm = fmaxf(s0v, s1v);
      tm = fmaxf(tm, __shfl_xor(tm, 1));
      tm = fmaxf(tm, __shfl_xor(tm, 2));
      tm = fmaxf(tm, __shfl_xor(tm, 4));
      tm = fmaxf(tm, __shfl_xor(tm, 8));
      float mnew = fmaxf(m[r], tm);
      float corr = __expf(m[r] - mnew);
      float e0 = __expf(s0v - mnew);
      float e1 = __expf(s1v - mnew);
      float rs = e0 + e1;
      rs += __shfl_xor(rs, 1);
      rs += __shfl_xor(rs, 2);
      rs += __shfl_xor(rs, 4);
      rs += __shfl_xor(rs, 8);
      l[r] = l[r] * corr + rs;
      m[r] = mnew;
      p0[r] = e0; p1[r] = e1;
#pragma unroll
      for (int nt = 0; nt < 4; ++nt) oacc[nt][r] *= corr;
    }

    // P (16x32) to LDS in D-layout; reread in A-layout
#pragma unroll
    for (int r = 0; r < 4; ++r) {
      P_lds[(g * 4 + r) * 40 + li]      = f2b(p0[r]);
      P_lds[(g * 4 + r) * 40 + 16 + li] = f2b(p1[r]);
    }
    __syncthreads();

    bf16x8 pf = *(const bf16x8*)&P_lds[li * 40 + g * 8];
#pragma unroll
    for (int nt = 0; nt < 4; ++nt) {
      bf16x8 vf = *(const bf16x8*)&Vt_lds[(nt * 16 + li) * 40 + g * 8];
      oacc[nt] = __builtin_amdgcn_mfma_f32_16x16x32_bf16(pf, vf, oacc[nt], 0, 0, 0);
    }
    __syncthreads();  // before next tile overwrites P_lds / Vt_lds
  }

  // epilogue: O[s][h*64+d] = oacc / l
#pragma unroll
  for (int nt = 0; nt < 4; ++nt)
#pragma unroll
    for (int r = 0; r < 4; ++r) {
      int s = s0 + g * 4 + r;
      int d = nt * 16 + li;
      O[((size_t)(b * S_ + s) * NH + h) * HD_ + d] = f2b(oacc[nt][r] / l[r]);
    }
}

// ---------------- launch ----------------
extern "C" void kernel_launch(void* const* d_in, const int* in_sizes, int n_in,
                              void* d_out, int out_size, void* d_ws, size_t ws_size,
                              hipStream_t stream) {
  (void)in_sizes; (void)n_in; (void)out_size; (void)ws_size;
  const float* x  = (const float*)d_in[0];
  const float* Wq = (const float*)d_in[1];
  const float* Wk = (const float*)d_in[2];
  const float* Wv = (const float*)d_in[3];
  const float* Wo = (const float*)d_in[4];
  float* out = (float*)d_out;

  const size_t M = (size_t)B_ * S_;  // 4096
  u16* xb  = (u16*)d_ws;                         // M x 1024
  u16* WqT = xb  + M * DIN;                      // 1024 x 1024
  u16* WkT = WqT + (size_t)HID * DIN;            // 256 x 1024
  u16* WvT = WkT + (size_t)NKV * HD_ * DIN;      // 256 x 1024
  u16* WoT = WvT + (size_t)NKV * HD_ * DIN;      // 1024 x 1024
  u16* Qb  = WoT + (size_t)HID * HID;            // M x 1024
  u16* Kb  = Qb  + M * HID;                      // M x 256
  u16* Vb  = Kb  + M * (NKV * HD_);              // M x 256
  u16* Ob  = Vb  + M * (NKV * HD_);              // M x 1024
  // total ~33 MB

  k_cvt<<<dim3((int)(M * DIN / 256)), 256, 0, stream>>>(x, xb, (int)(M * DIN));
  k_cvt_t<<<dim3(DIN / 32, HID / 8),        256, 0, stream>>>(Wq, WqT, DIN, HID);
  k_cvt_t<<<dim3(DIN / 32, (NKV*HD_) / 8),  256, 0, stream>>>(Wk, WkT, DIN, NKV * HD_);
  k_cvt_t<<<dim3(DIN / 32, (NKV*HD_) / 8),  256, 0, stream>>>(Wv, WvT, DIN, NKV * HD_);
  k_cvt_t<<<dim3(HID / 32, HID / 8),        256, 0, stream>>>(Wo, WoT, HID, HID);

  k_gemm_bt<u16><<<dim3(HID / 128, (int)(M / 128)), 256, 0, stream>>>(xb, WqT, Qb, (int)M, HID, DIN);
  k_gemm_bt<u16><<<dim3((NKV*HD_) / 128, (int)(M / 128)), 256, 0, stream>>>(xb, WkT, Kb, (int)M, NKV * HD_, DIN);
  k_gemm_bt<u16><<<dim3((NKV*HD_) / 128, (int)(M / 128)), 256, 0, stream>>>(xb, WvT, Vb, (int)M, NKV * HD_, DIN);

  k_attn<<<dim3(S_ / 16, NH, B_), 64, 0, stream>>>(Qb, Kb, Vb, Ob);

  k_gemm_bt<float><<<dim3(HID / 128, (int)(M / 128)), 256, 0, stream>>>(Ob, WoT, out, (int)M, HID, HID);
}

// Round 2
// 194.847 us; speedup vs baseline: 1.7339x; 1.7339x over previous
//
#include <hip/hip_runtime.h>

using u16 = unsigned short;
using u32 = unsigned int;
typedef __bf16 bf16x8 __attribute__((ext_vector_type(8)));
typedef u16 u16x8 __attribute__((ext_vector_type(8)));
typedef float f32x4 __attribute__((ext_vector_type(4)));

#define B_   2
#define S_   2048
#define DIN  1024
#define HID  1024
#define NH   16
#define NKV  4
#define HD_  64
#define QKVW 1536
#define SCALE_ 0.125f

__device__ __forceinline__ u16 f2b(float f) {
  u32 u = __builtin_bit_cast(u32, f);
  u32 r = (u + 0x7FFFu + ((u >> 16) & 1u)) >> 16;
  return (u16)r;
}

// ---------------- converters ----------------
__global__ void k_cvt(const float* __restrict__ in, u16* __restrict__ out, int n) {
  int i = blockIdx.x * 256 + threadIdx.x;
  if (i < n) out[i] = f2b(in[i]);
}

// W is K x N row-major (in,out). WT[n][k] = bf16(W[k][n]).
__global__ void k_cvt_t(const float* __restrict__ W, u16* __restrict__ WT, int K, int N) {
  int k = blockIdx.x * 32 + (threadIdx.x & 31);
  int n = blockIdx.y * 8 + (threadIdx.x >> 5);
  WT[(size_t)n * K + k] = f2b(W[(size_t)k * N + n]);
}

// ---------------- GEMM: C = A * Bt^T ----------------
template <typename OutT>
__global__ __launch_bounds__(256) void k_gemm_bt(
    const u16* __restrict__ A, const u16* __restrict__ Bt,
    OutT* __restrict__ C, int M, int N, int K)
{
  constexpr int LD = 40;
  __shared__ u16 lA[128 * LD];
  __shared__ u16 lB[128 * LD];
  const int tid  = threadIdx.x;
  const int lane = tid & 63;
  const int wave = tid >> 6;
  const int wm = wave >> 1, wn = wave & 1;
  const int g = lane >> 4, li = lane & 15;
  const int bm = blockIdx.y * 128, bn = blockIdx.x * 128;
  const int srow = tid >> 2, scol = (tid & 3) * 8;

  f32x4 acc[4][4];
#pragma unroll
  for (int i = 0; i < 4; ++i)
#pragma unroll
    for (int j = 0; j < 4; ++j) acc[i][j] = f32x4{0.f, 0.f, 0.f, 0.f};

  const u16* Ab = A + (size_t)bm * K;
  const u16* Bb = Bt + (size_t)bn * K;

  for (int k0 = 0; k0 < K; k0 += 32) {
    __syncthreads();
#pragma unroll
    for (int h = 0; h < 2; ++h) {
      u16x8 av = *(const u16x8*)&Ab[(size_t)(h * 64 + srow) * K + k0 + scol];
      u16x8 bv = *(const u16x8*)&Bb[(size_t)(h * 64 + srow) * K + k0 + scol];
      *(u16x8*)&lA[(h * 64 + srow) * LD + scol] = av;
      *(u16x8*)&lB[(h * 64 + srow) * LD + scol] = bv;
    }
    __syncthreads();
    bf16x8 af[4], bfr[4];
#pragma unroll
    for (int mt = 0; mt < 4; ++mt)
      af[mt] = *(const bf16x8*)&lA[(wm * 64 + mt * 16 + li) * LD + g * 8];
#pragma unroll
    for (int nt = 0; nt < 4; ++nt)
      bfr[nt] = *(const bf16x8*)&lB[(wn * 64 + nt * 16 + li) * LD + g * 8];
#pragma unroll
    for (int mt = 0; mt < 4; ++mt)
#pragma unroll
      for (int nt = 0; nt < 4; ++nt)
        acc[mt][nt] = __builtin_amdgcn_mfma_f32_16x16x32_bf16(af[mt], bfr[nt], acc[mt][nt], 0, 0, 0);
  }

#pragma unroll
  for (int mt = 0; mt < 4; ++mt)
#pragma unroll
    for (int nt = 0; nt < 4; ++nt)
#pragma unroll
      for (int r = 0; r < 4; ++r) {
        int row = bm + wm * 64 + mt * 16 + g * 4 + r;
        int col = bn + wn * 64 + nt * 16 + li;
        float v = acc[mt][nt][r];
        if constexpr (sizeof(OutT) == 4) C[(size_t)row * N + col] = v;
        else                             C[(size_t)row * N + col] = f2b(v);
      }
}

// ---------------- flash attention ----------------
// QKV fused: (B*S, 1536) bf16 rows: [Q(1024) | K(256) | V(256)].
// Block: 8 waves = 4 query heads x 2 rowgroups(16) covering 32 Q rows of one
// KV group. K/V staged in LDS once per tile, shared by all 8 waves.
// grid (S/32, NKV, B), block 512.
__global__ __launch_bounds__(512) void k_attn(
    const u16* __restrict__ QKV, u16* __restrict__ O)
{
  constexpr int LD = 72;   // row stride (u16): b128 reads at bank BW floor
  __shared__ u16 K_lds[64 * LD];
  __shared__ u16 Vt_lds[64 * LD];
  __shared__ u16 P_lds[8 * 16 * LD];
  const int tid  = threadIdx.x;
  const int lane = tid & 63;
  const int w    = tid >> 6;
  const int g = lane >> 4, li = lane & 15;
  const int s0 = blockIdx.x * 32;
  const int kv = blockIdx.y;
  const int b  = blockIdx.z;
  const int hq = kv * 4 + (w & 3);
  const int rg = w >> 2;
  u16* Pw = &P_lds[w * 16 * LD];

  // Q fragments (row s0+rg*16+li, k-dim = kk*32 + g*8 + j), hoisted
  bf16x8 qf[2];
  {
    const u16* qb = QKV + (size_t)(b * S_ + s0 + rg * 16 + li) * QKVW + hq * HD_ + g * 8;
    qf[0] = *(const bf16x8*)(qb);
    qf[1] = *(const bf16x8*)(qb + 32);
  }

  float m[4], l[4];
  f32x4 oacc[4];
#pragma unroll
  for (int r = 0; r < 4; ++r) { m[r] = -1e30f; l[r] = 0.f; }
#pragma unroll
  for (int nt = 0; nt < 4; ++nt) oacc[nt] = f32x4{0.f, 0.f, 0.f, 0.f};

  // staging assignments (512 threads, 64x64 tile each for K and V)
  const int kt = tid >> 3, kc = (tid & 7) * 8;       // K: row kt, cols kc..kc+7
  const u16* kgb = QKV + (size_t)(b * S_ + kt) * QKVW + HID + kv * HD_ + kc;
  const int vt = tid & 63, vd = (tid >> 6) * 8;      // V: row vt, cols vd..vd+7
  const u16* vgb = QKV + (size_t)(b * S_ + vt) * QKVW + HID + NKV * HD_ + kv * HD_ + vd;

  for (int t0 = 0; t0 < S_; t0 += 64) {
    // issue next-tile global loads before waiting on the barrier
    u16x8 kvec = *(const u16x8*)(kgb + (size_t)t0 * QKVW);
    u16x8 vvec = *(const u16x8*)(vgb + (size_t)t0 * QKVW);
    __syncthreads();  // all waves done reading previous K/Vt tile
    *(u16x8*)&K_lds[kt * LD + kc] = kvec;
#pragma unroll
    for (int e = 0; e < 8; ++e) Vt_lds[(vd + e) * LD + vt] = vvec[e];  // contiguous across lanes
    __syncthreads();

    // QK^T: st[tc] covers keys tc*16+li (cols), rows g*4+r
    f32x4 st[4];
#pragma unroll
    for (int tc = 0; tc < 4; ++tc) {
      st[tc] = f32x4{0.f, 0.f, 0.f, 0.f};
#pragma unroll
      for (int kk = 0; kk < 2; ++kk) {
        bf16x8 kf = *(const bf16x8*)&K_lds[(tc * 16 + li) * LD + kk * 32 + g * 8];
        st[tc] = __builtin_amdgcn_mfma_f32_16x16x32_bf16(qf[kk], kf, st[tc], 0, 0, 0);
      }
    }

    // online softmax over 64 keys (4 rows per lane-group)
#pragma unroll
    for (int r = 0; r < 4; ++r) {
      float sv[4];
#pragma unroll
      for (int tc = 0; tc < 4; ++tc) sv[tc] = st[tc][r] * SCALE_;
      float tm = fmaxf(fmaxf(sv[0], sv[1]), fmaxf(sv[2], sv[3]));
      tm = fmaxf(tm, __shfl_xor(tm, 1));
      tm = fmaxf(tm, __shfl_xor(tm, 2));
      tm = fmaxf(tm, __shfl_xor(tm, 4));
      tm = fmaxf(tm, __shfl_xor(tm, 8));
      float mnew = fmaxf(m[r], tm);
      float corr = __expf(m[r] - mnew);
      float e0 = __expf(sv[0] - mnew);
      float e1 = __expf(sv[1] - mnew);
      float e2 = __expf(sv[2] - mnew);
      float e3 = __expf(sv[3] - mnew);
      float rs = (e0 + e1) + (e2 + e3);
      rs += __shfl_xor(rs, 1);
      rs += __shfl_xor(rs, 2);
      rs += __shfl_xor(rs, 4);
      rs += __shfl_xor(rs, 8);
      l[r] = l[r] * corr + rs;
      m[r] = mnew;
      Pw[(g * 4 + r) * LD + li]      = f2b(e0);
      Pw[(g * 4 + r) * LD + 16 + li] = f2b(e1);
      Pw[(g * 4 + r) * LD + 32 + li] = f2b(e2);
      Pw[(g * 4 + r) * LD + 48 + li] = f2b(e3);
#pragma unroll
      for (int nt = 0; nt < 4; ++nt) oacc[nt][r] *= corr;
    }

    asm volatile("s_waitcnt lgkmcnt(0)" ::: "memory");  // P writes visible to wave

    // PV: O += P(16x64) * V(64x64)
#pragma unroll
    for (int kk = 0; kk < 2; ++kk) {
      bf16x8 pf = *(const bf16x8*)&Pw[li * LD + kk * 32 + g * 8];
#pragma unroll
      for (int nt = 0; nt < 4; ++nt) {
        bf16x8 vf = *(const bf16x8*)&Vt_lds[(nt * 16 + li) * LD + kk * 32 + g * 8];
        oacc[nt] = __builtin_amdgcn_mfma_f32_16x16x32_bf16(pf, vf, oacc[nt], 0, 0, 0);
      }
    }
  }

  // epilogue: O[s][hq*64+d] = oacc / l
#pragma unroll
  for (int nt = 0; nt < 4; ++nt)
#pragma unroll
    for (int r = 0; r < 4; ++r) {
      int s = s0 + rg * 16 + g * 4 + r;
      int d = nt * 16 + li;
      O[(size_t)(b * S_ + s) * HID + hq * HD_ + d] = f2b(oacc[nt][r] / l[r]);
    }
}

// ---------------- launch ----------------
extern "C" void kernel_launch(void* const* d_in, const int* in_sizes, int n_in,
                              void* d_out, int out_size, void* d_ws, size_t ws_size,
                              hipStream_t stream) {
  (void)in_sizes; (void)n_in; (void)out_size; (void)ws_size;
  const float* x  = (const float*)d_in[0];
  const float* Wq = (const float*)d_in[1];
  const float* Wk = (const float*)d_in[2];
  const float* Wv = (const float*)d_in[3];
  const float* Wo = (const float*)d_in[4];
  float* out = (float*)d_out;

  const size_t M = (size_t)B_ * S_;  // 4096
  u16* xb    = (u16*)d_ws;                        // M x 1024
  u16* WqkvT = xb    + M * DIN;                   // 1536 x 1024  (rows: Wq cols, Wk cols, Wv cols)
  u16* WoT   = WqkvT + (size_t)QKVW * DIN;        // 1024 x 1024
  u16* QKV   = WoT   + (size_t)HID * HID;         // M x 1536
  u16* Ob    = QKV   + M * QKVW;                  // M x 1024

  k_cvt<<<dim3((int)(M * DIN / 256)), 256, 0, stream>>>(x, xb, (int)(M * DIN));
  k_cvt_t<<<dim3(DIN / 32, HID / 8),       256, 0, stream>>>(Wq, WqkvT,                      DIN, HID);
  k_cvt_t<<<dim3(DIN / 32, (NKV*HD_) / 8), 256, 0, stream>>>(Wk, WqkvT + (size_t)HID * DIN,  DIN, NKV * HD_);
  k_cvt_t<<<dim3(DIN / 32, (NKV*HD_) / 8), 256, 0, stream>>>(Wv, WqkvT + (size_t)(HID + NKV*HD_) * DIN, DIN, NKV * HD_);
  k_cvt_t<<<dim3(HID / 32, HID / 8),       256, 0, stream>>>(Wo, WoT, HID, HID);

  // fused QKV projection: (M x 1024) * (1024 x 1536) -> M x 1536
  k_gemm_bt<u16><<<dim3(QKVW / 128, (int)(M / 128)), 256, 0, stream>>>(xb, WqkvT, QKV, (int)M, QKVW, DIN);

  k_attn<<<dim3(S_ / 32, NKV, B_), 512, 0, stream>>>(QKV, Ob);

  k_gemm_bt<float><<<dim3(HID / 128, (int)(M / 128)), 256, 0, stream>>>(Ob, WoT, out, (int)M, HID, HID);
}

// Round 3
// 163.129 us; speedup vs baseline: 2.0711x; 1.1944x over previous
//
#include <hip/hip_runtime.h>

using u16 = unsigned short;
using u32 = unsigned int;
typedef __bf16 bf16x8 __attribute__((ext_vector_type(8)));
typedef u16 u16x8 __attribute__((ext_vector_type(8)));
typedef float f32x4 __attribute__((ext_vector_type(4)));

#define B_   2
#define S_   2048
#define DIN  1024
#define HID  1024
#define NH   16
#define NKV  4
#define HD_  64
#define QKVW 1536
// 0.125 * log2(e): folded into Q so softmax runs in exp2 domain
#define QSCL 0.1803368801111244f

__device__ __forceinline__ u16 f2b(float f) {
  u32 u = __builtin_bit_cast(u32, f);
  u32 r = (u + 0x7FFFu + ((u >> 16) & 1u)) >> 16;
  return (u16)r;
}

// ---------------- converters ----------------
// 8 floats per thread
__global__ void k_cvt(const float* __restrict__ in, u16* __restrict__ out, int n8) {
  int i = blockIdx.x * 256 + threadIdx.x;
  if (i >= n8) return;
  const float4* p = (const float4*)(in + (size_t)i * 8);
  float4 a = p[0], b = p[1];
  u16x8 o;
  o[0] = f2b(a.x); o[1] = f2b(a.y); o[2] = f2b(a.z); o[3] = f2b(a.w);
  o[4] = f2b(b.x); o[5] = f2b(b.y); o[6] = f2b(b.z); o[7] = f2b(b.w);
  *(u16x8*)(out + (size_t)i * 8) = o;
}

// W is K x N row-major (in,out). WT[n][k] = bf16(W[k][n]). LDS 32x32 tile transpose.
__global__ __launch_bounds__(256) void k_cvt_t(const float* __restrict__ W, u16* __restrict__ WT, int K, int N) {
  __shared__ float t[32][33];
  const int k0 = blockIdx.x * 32, n0 = blockIdx.y * 32;
  const int c = threadIdx.x & 31, r8 = threadIdx.x >> 5;
#pragma unroll
  for (int i = 0; i < 4; ++i)
    t[r8 + i * 8][c] = W[(size_t)(k0 + r8 + i * 8) * N + n0 + c];
  __syncthreads();
#pragma unroll
  for (int i = 0; i < 4; ++i)
    WT[(size_t)(n0 + r8 + i * 8) * K + k0 + c] = f2b(t[c][r8 + i * 8]);
}

// ---------------- GEMM: C = A * Bt^T ----------------
// cols < scaleCols get multiplied by scl in the epilogue.
template <typename OutT>
__global__ __launch_bounds__(256) void k_gemm_bt(
    const u16* __restrict__ A, const u16* __restrict__ Bt,
    OutT* __restrict__ C, int M, int N, int K, int scaleCols, float scl)
{
  constexpr int LD = 40;
  __shared__ u16 lA[128 * LD];
  __shared__ u16 lB[128 * LD];
  const int tid  = threadIdx.x;
  const int lane = tid & 63;
  const int wave = tid >> 6;
  const int wm = wave >> 1, wn = wave & 1;
  const int g = lane >> 4, li = lane & 15;
  const int bm = blockIdx.y * 128, bn = blockIdx.x * 128;
  const int srow = tid >> 2, scol = (tid & 3) * 8;

  f32x4 acc[4][4];
#pragma unroll
  for (int i = 0; i < 4; ++i)
#pragma unroll
    for (int j = 0; j < 4; ++j) acc[i][j] = f32x4{0.f, 0.f, 0.f, 0.f};

  const u16* Ab = A + (size_t)bm * K;
  const u16* Bb = Bt + (size_t)bn * K;

  for (int k0 = 0; k0 < K; k0 += 32) {
    __syncthreads();
#pragma unroll
    for (int h = 0; h < 2; ++h) {
      u16x8 av = *(const u16x8*)&Ab[(size_t)(h * 64 + srow) * K + k0 + scol];
      u16x8 bv = *(const u16x8*)&Bb[(size_t)(h * 64 + srow) * K + k0 + scol];
      *(u16x8*)&lA[(h * 64 + srow) * LD + scol] = av;
      *(u16x8*)&lB[(h * 64 + srow) * LD + scol] = bv;
    }
    __syncthreads();
    bf16x8 af[4], bfr[4];
#pragma unroll
    for (int mt = 0; mt < 4; ++mt)
      af[mt] = *(const bf16x8*)&lA[(wm * 64 + mt * 16 + li) * LD + g * 8];
#pragma unroll
    for (int nt = 0; nt < 4; ++nt)
      bfr[nt] = *(const bf16x8*)&lB[(wn * 64 + nt * 16 + li) * LD + g * 8];
#pragma unroll
    for (int mt = 0; mt < 4; ++mt)
#pragma unroll
      for (int nt = 0; nt < 4; ++nt)
        acc[mt][nt] = __builtin_amdgcn_mfma_f32_16x16x32_bf16(af[mt], bfr[nt], acc[mt][nt], 0, 0, 0);
  }

#pragma unroll
  for (int mt = 0; mt < 4; ++mt)
#pragma unroll
    for (int nt = 0; nt < 4; ++nt)
#pragma unroll
      for (int r = 0; r < 4; ++r) {
        int row = bm + wm * 64 + mt * 16 + g * 4 + r;
        int col = bn + wn * 64 + nt * 16 + li;
        float v = acc[mt][nt][r];
        if (col < scaleCols) v *= scl;
        if constexpr (sizeof(OutT) == 4) C[(size_t)row * N + col] = v;
        else                             C[(size_t)row * N + col] = f2b(v);
      }
}

// ---------------- flash attention (swapped QK^T, in-register softmax) ----------------
// QKV fused: (B*S, 1536) bf16 rows: [Q(1024, pre-scaled by QSCL) | K(256) | V(256)].
// Block: 8 waves = 4 query heads x 2 rowgroups(16 Q rows). K/V staged once per
// tile (XOR-swizzled LDS), shared by 8 waves. grid (S/32, NKV, B), block 512.
__global__ __launch_bounds__(512) void k_attn(
    const u16* __restrict__ QKV, u16* __restrict__ O)
{
  __shared__ u16 K_lds[64 * 64];
  __shared__ u16 Vt_lds[64 * 64];
  __shared__ u16 P_lds[8 * 16 * 64];
  const int tid  = threadIdx.x;
  const int lane = tid & 63;
  const int w    = tid >> 6;
  const int g = lane >> 4, li = lane & 15;
  const int sw = (li & 7) << 3;          // u16-index XOR swizzle for this lane's rows
  const int s0 = blockIdx.x * 32;
  const int kv = blockIdx.y;
  const int b  = blockIdx.z;
  const int hq = kv * 4 + (w & 3);
  const int rg = w >> 2;
  u16* Pw = &P_lds[w * 16 * 64];

  // Q fragment (query col = li, d = kk*32 + g*8 + j) -- same bytes as an A-frag load
  bf16x8 qf[2];
  {
    const u16* qb = QKV + (size_t)(b * S_ + s0 + rg * 16 + li) * QKVW + hq * HD_ + g * 8;
    qf[0] = *(const bf16x8*)(qb);
    qf[1] = *(const bf16x8*)(qb + 32);
  }

  float m = -1e30f, l = 0.f;
  f32x4 oacc[4];
#pragma unroll
  for (int nt = 0; nt < 4; ++nt) oacc[nt] = f32x4{0.f, 0.f, 0.f, 0.f};

  // staging assignments (512 threads; 64x64 K tile + 64x64 V^T tile)
  const int kt = tid >> 3, kc = (tid & 7) * 8;
  const u16* kgb = QKV + (size_t)(b * S_ + kt) * QKVW + HID + kv * HD_ + kc;
  const int vt = tid & 63, vd = (tid >> 6) * 8;
  const u16* vgb = QKV + (size_t)(b * S_ + vt) * QKVW + HID + NKV * HD_ + kv * HD_ + vd;
  const int kdst = kt * 64 + (kc ^ ((kt & 7) << 3));

  for (int t0 = 0; t0 < S_; t0 += 64) {
    // issue next-tile global loads before the barrier (hide HBM under prior compute)
    u16x8 kvec = *(const u16x8*)(kgb + (size_t)t0 * QKVW);
    u16x8 vvec = *(const u16x8*)(vgb + (size_t)t0 * QKVW);
    __syncthreads();  // all waves done reading previous K/Vt tile
    *(u16x8*)&K_lds[kdst] = kvec;
#pragma unroll
    for (int e = 0; e < 8; ++e)
      Vt_lds[(vd + e) * 64 + (vt ^ (((vd + e) & 7) << 3))] = vvec[e];
    __syncthreads();

    // S^T = K * Q^T: st[tc][r] = score(key=t0+tc*16+g*4+r, query=li) in log2 units
    f32x4 st[4];
#pragma unroll
    for (int tc = 0; tc < 4; ++tc) {
      st[tc] = f32x4{0.f, 0.f, 0.f, 0.f};
#pragma unroll
      for (int kk = 0; kk < 2; ++kk) {
        bf16x8 kf = *(const bf16x8*)&K_lds[(tc * 16 + li) * 64 + ((kk * 32 + g * 8) ^ sw)];
        st[tc] = __builtin_amdgcn_mfma_f32_16x16x32_bf16(kf, qf[kk], st[tc], 0, 0, 0);
      }
    }

    // in-register online softmax for query li (16 scores/lane; combine 4 g-lanes)
    float tm = fmaxf(fmaxf(st[0][0], st[0][1]), fmaxf(st[0][2], st[0][3]));
#pragma unroll
    for (int tc = 1; tc < 4; ++tc)
      tm = fmaxf(tm, fmaxf(fmaxf(st[tc][0], st[tc][1]), fmaxf(st[tc][2], st[tc][3])));
    tm = fmaxf(tm, __shfl_xor(tm, 16));
    tm = fmaxf(tm, __shfl_xor(tm, 32));
    float mnew = fmaxf(m, tm);
    float corr = exp2f(m - mnew);
    float rs = 0.f;
#pragma unroll
    for (int tc = 0; tc < 4; ++tc) {
      float p0 = exp2f(st[tc][0] - mnew);
      float p1 = exp2f(st[tc][1] - mnew);
      float p2 = exp2f(st[tc][2] - mnew);
      float p3 = exp2f(st[tc][3] - mnew);
      rs += (p0 + p1) + (p2 + p3);
      u32 w0 = (u32)f2b(p0) | ((u32)f2b(p1) << 16);
      u32 w1 = (u32)f2b(p2) | ((u32)f2b(p3) << 16);
      *(u32*)&Pw[li * 64 + ((tc * 16 + g * 4)     ^ sw)] = w0;
      *(u32*)&Pw[li * 64 + ((tc * 16 + g * 4 + 2) ^ sw)] = w1;
    }
    rs += __shfl_xor(rs, 16);
    rs += __shfl_xor(rs, 32);
    l = l * corr + rs;
    m = mnew;

    // broadcast corr to the lanes owning output row (query-local g*4+r)
    float cr[4];
#pragma unroll
    for (int r = 0; r < 4; ++r) cr[r] = __shfl(corr, g * 4 + r);
#pragma unroll
    for (int nt = 0; nt < 4; ++nt)
#pragma unroll
      for (int r = 0; r < 4; ++r) oacc[nt][r] *= cr[r];

    asm volatile("s_waitcnt lgkmcnt(0)" ::: "memory");  // wave's P writes visible

    // O += P(16x64) * V(64x64)
#pragma unroll
    for (int kk = 0; kk < 2; ++kk) {
      bf16x8 pf = *(const bf16x8*)&Pw[li * 64 + ((kk * 32 + g * 8) ^ sw)];
#pragma unroll
      for (int nt = 0; nt < 4; ++nt) {
        bf16x8 vf = *(const bf16x8*)&Vt_lds[(nt * 16 + li) * 64 + ((kk * 32 + g * 8) ^ sw)];
        oacc[nt] = __builtin_amdgcn_mfma_f32_16x16x32_bf16(pf, vf, oacc[nt], 0, 0, 0);
      }
    }
  }

  // epilogue
  float lr[4];
#pragma unroll
  for (int r = 0; r < 4; ++r) lr[r] = __shfl(l, g * 4 + r);
#pragma unroll
  for (int nt = 0; nt < 4; ++nt)
#pragma unroll
    for (int r = 0; r < 4; ++r) {
      int s = s0 + rg * 16 + g * 4 + r;
      int d = nt * 16 + li;
      O[(size_t)(b * S_ + s) * HID + hq * HD_ + d] = f2b(oacc[nt][r] / lr[r]);
    }
}

// ---------------- launch ----------------
extern "C" void kernel_launch(void* const* d_in, const int* in_sizes, int n_in,
                              void* d_out, int out_size, void* d_ws, size_t ws_size,
                              hipStream_t stream) {
  (void)in_sizes; (void)n_in; (void)out_size; (void)ws_size;
  const float* x  = (const float*)d_in[0];
  const float* Wq = (const float*)d_in[1];
  const float* Wk = (const float*)d_in[2];
  const float* Wv = (const float*)d_in[3];
  const float* Wo = (const float*)d_in[4];
  float* out = (float*)d_out;

  const size_t M = (size_t)B_ * S_;  // 4096
  u16* xb    = (u16*)d_ws;                        // M x 1024
  u16* WqkvT = xb    + M * DIN;                   // 1536 x 1024
  u16* WoT   = WqkvT + (size_t)QKVW * DIN;        // 1024 x 1024
  u16* QKV   = WoT   + (size_t)HID * HID;         // M x 1536
  u16* Ob    = QKV   + M * QKVW;                  // M x 1024

  k_cvt<<<dim3((int)(M * DIN / 8 / 256)), 256, 0, stream>>>(x, xb, (int)(M * DIN / 8));
  k_cvt_t<<<dim3(DIN / 32, HID / 32),       256, 0, stream>>>(Wq, WqkvT,                      DIN, HID);
  k_cvt_t<<<dim3(DIN / 32, (NKV*HD_) / 32), 256, 0, stream>>>(Wk, WqkvT + (size_t)HID * DIN,  DIN, NKV * HD_);
  k_cvt_t<<<dim3(DIN / 32, (NKV*HD_) / 32), 256, 0, stream>>>(Wv, WqkvT + (size_t)(HID + NKV*HD_) * DIN, DIN, NKV * HD_);
  k_cvt_t<<<dim3(HID / 32, HID / 32),       256, 0, stream>>>(Wo, WoT, HID, HID);

  // fused QKV projection; Q columns pre-scaled by 0.125*log2(e)
  k_gemm_bt<u16><<<dim3(QKVW / 128, (int)(M / 128)), 256, 0, stream>>>(
      xb, WqkvT, QKV, (int)M, QKVW, DIN, HID, QSCL);

  k_attn<<<dim3(S_ / 32, NKV, B_), 512, 0, stream>>>(QKV, Ob);

  k_gemm_bt<float><<<dim3(HID / 128, (int)(M / 128)), 256, 0, stream>>>(
      Ob, WoT, out, (int)M, HID, HID, 0, 1.0f);
}

// Round 4
// 136.205 us; speedup vs baseline: 2.4805x; 1.1977x over previous
//
#include <hip/hip_runtime.h>

using u16 = unsigned short;
using u32 = unsigned int;
typedef __bf16 bf16x8 __attribute__((ext_vector_type(8)));
typedef u16 u16x8 __attribute__((ext_vector_type(8)));
typedef u32 u32x2 __attribute__((ext_vector_type(2)));
typedef float f32x4 __attribute__((ext_vector_type(4)));

#define B_   2
#define S_   2048
#define DIN  1024
#define HID  1024
#define NH   16
#define NKV  4
#define HD_  64
#define QKVW 1536
// 0.125 * log2(e): folded into Q so softmax runs in exp2 domain
#define QSCL 0.1803368801111244f

__device__ __forceinline__ u16 f2b(float f) {
  u32 u = __builtin_bit_cast(u32, f);
  u32 r = (u + 0x7FFFu + ((u >> 16) & 1u)) >> 16;
  return (u16)r;
}

// async global->LDS, 16B per lane; dst is wave-uniform base + lane*16
__device__ __forceinline__ void gl16(const void* g, void* l) {
  __builtin_amdgcn_global_load_lds(
      (const __attribute__((address_space(1))) void*)g,
      (__attribute__((address_space(3))) void*)l, 16, 0, 0);
}

// ---------------- converters ----------------
__global__ void k_cvt(const float* __restrict__ in, u16* __restrict__ out, int n8) {
  int i = blockIdx.x * 256 + threadIdx.x;
  if (i >= n8) return;
  const float4* p = (const float4*)(in + (size_t)i * 8);
  float4 a = p[0], b = p[1];
  u16x8 o;
  o[0] = f2b(a.x); o[1] = f2b(a.y); o[2] = f2b(a.z); o[3] = f2b(a.w);
  o[4] = f2b(b.x); o[5] = f2b(b.y); o[6] = f2b(b.z); o[7] = f2b(b.w);
  *(u16x8*)(out + (size_t)i * 8) = o;
}

// W is K x N row-major (in,out). WT[n][k] = bf16(W[k][n]). LDS 32x32 tile transpose.
__global__ __launch_bounds__(256) void k_cvt_t(const float* __restrict__ W, u16* __restrict__ WT, int K, int N) {
  __shared__ float t[32][33];
  const int k0 = blockIdx.x * 32, n0 = blockIdx.y * 32;
  const int c = threadIdx.x & 31, r8 = threadIdx.x >> 5;
#pragma unroll
  for (int i = 0; i < 4; ++i)
    t[r8 + i * 8][c] = W[(size_t)(k0 + r8 + i * 8) * N + n0 + c];
  __syncthreads();
#pragma unroll
  for (int i = 0; i < 4; ++i)
    WT[(size_t)(n0 + r8 + i * 8) * K + k0 + c] = f2b(t[c][r8 + i * 8]);
}

// ---------------- GEMM: C = A * Bt^T (m97-style global_load_lds staging) ----------------
template <typename OutT>
__global__ __launch_bounds__(256) void k_gemm_bt(
    const u16* __restrict__ A, const u16* __restrict__ Bt,
    OutT* __restrict__ C, int M, int N, int K, int scaleCols, float scl)
{
  __shared__ u16 lA[128 * 32];
  __shared__ u16 lB[128 * 32];
  const int tid  = threadIdx.x;
  const int lane = tid & 63;
  const int wave = tid >> 6;
  const int wm = wave >> 1, wn = wave & 1;
  const int g = lane >> 4, li = lane & 15;
  const int bm = blockIdx.y * 128, bn = blockIdx.x * 128;
  // staging: instr h covers LDS bytes [h*4096 + wave*1024, +1024); lane l -> +l*16
  const int srow = wave * 16 + (lane >> 2);     // + h*64
  const int scol = (lane & 3) * 8;

  f32x4 acc[4][4];
#pragma unroll
  for (int i = 0; i < 4; ++i)
#pragma unroll
    for (int j = 0; j < 4; ++j) acc[i][j] = f32x4{0.f, 0.f, 0.f, 0.f};

  const u16* Ab = A + (size_t)bm * K;
  const u16* Bb = Bt + (size_t)bn * K;

  for (int k0 = 0; k0 < K; k0 += 32) {
    __syncthreads();
#pragma unroll
    for (int h = 0; h < 2; ++h) {
      gl16(&Ab[(size_t)(h * 64 + srow) * K + k0 + scol], (char*)lA + h * 4096 + wave * 1024);
      gl16(&Bb[(size_t)(h * 64 + srow) * K + k0 + scol], (char*)lB + h * 4096 + wave * 1024);
    }
    __syncthreads();  // drains vmcnt before barrier
    bf16x8 af[4], bfr[4];
#pragma unroll
    for (int mt = 0; mt < 4; ++mt)
      af[mt] = *(const bf16x8*)&lA[(wm * 64 + mt * 16 + li) * 32 + g * 8];
#pragma unroll
    for (int nt = 0; nt < 4; ++nt)
      bfr[nt] = *(const bf16x8*)&lB[(wn * 64 + nt * 16 + li) * 32 + g * 8];
    __builtin_amdgcn_s_setprio(1);
#pragma unroll
    for (int mt = 0; mt < 4; ++mt)
#pragma unroll
      for (int nt = 0; nt < 4; ++nt)
        acc[mt][nt] = __builtin_amdgcn_mfma_f32_16x16x32_bf16(af[mt], bfr[nt], acc[mt][nt], 0, 0, 0);
    __builtin_amdgcn_s_setprio(0);
  }

#pragma unroll
  for (int mt = 0; mt < 4; ++mt)
#pragma unroll
    for (int nt = 0; nt < 4; ++nt)
#pragma unroll
      for (int r = 0; r < 4; ++r) {
        int row = bm + wm * 64 + mt * 16 + g * 4 + r;
        int col = bn + wn * 64 + nt * 16 + li;
        float v = acc[mt][nt][r];
        if (col < scaleCols) v *= scl;
        if constexpr (sizeof(OutT) == 4) C[(size_t)row * N + col] = v;
        else                             C[(size_t)row * N + col] = f2b(v);
      }
}

// ---------------- flash attention ----------------
// Swapped QK^T, in-register softmax (exp2 domain), XOR-swizzled LDS,
// K/V double-buffered with one barrier per tile, defer-max, setprio.
// grid (S/32, NKV, B), block 512 = 8 waves (4 heads x 2 rowgroups of 16).
__global__ __launch_bounds__(512) void k_attn(
    const u16* __restrict__ QKV, u16* __restrict__ O)
{
  __shared__ u16 K_lds[2][64 * 64];
  __shared__ u16 Vt_lds[2][64 * 64];
  __shared__ u16 P_lds[8 * 16 * 64];
  const int tid  = threadIdx.x;
  const int lane = tid & 63;
  const int w    = tid >> 6;
  const int g = lane >> 4, li = lane & 15;
  const int sw = (li & 7) << 3;
  const int s0 = blockIdx.x * 32;
  const int kv = blockIdx.y;
  const int b  = blockIdx.z;
  const int hq = kv * 4 + (w & 3);
  const int rg = w >> 2;
  u16* Pw = &P_lds[w * 16 * 64];

  bf16x8 qf[2];
  {
    const u16* qb = QKV + (size_t)(b * S_ + s0 + rg * 16 + li) * QKVW + hq * HD_ + g * 8;
    qf[0] = *(const bf16x8*)(qb);
    qf[1] = *(const bf16x8*)(qb + 32);
  }

  float m = -1e30f, l = 0.f;
  f32x4 oacc[4];
#pragma unroll
  for (int nt = 0; nt < 4; ++nt) oacc[nt] = f32x4{0.f, 0.f, 0.f, 0.f};

  const int kt = tid >> 3, kc = (tid & 7) * 8;
  const u16* kgb = QKV + (size_t)(b * S_ + kt) * QKVW + HID + kv * HD_ + kc;
  const int vt = tid & 63, vd = (tid >> 6) * 8;
  const u16* vgb = QKV + (size_t)(b * S_ + vt) * QKVW + HID + NKV * HD_ + kv * HD_ + vd;
  const int kdst = kt * 64 + (kc ^ ((kt & 7) << 3));

  // prologue: stage tile 0 into buffer 0
  {
    u16x8 kvec = *(const u16x8*)(kgb);
    u16x8 vvec = *(const u16x8*)(vgb);
    *(u16x8*)&K_lds[0][kdst] = kvec;
#pragma unroll
    for (int e = 0; e < 8; ++e)
      Vt_lds[0][(vd + e) * 64 + (vt ^ (((vd + e) & 7) << 3))] = vvec[e];
  }
  __syncthreads();

  constexpr int NT = S_ / 64;
  for (int t = 0; t < NT; ++t) {
    const int cur = t & 1;
    u16x8 kvec, vvec;
    const bool pref = (t + 1 < NT);
    if (pref) {  // issue next-tile loads; consumed after PV (latency hidden)
      kvec = *(const u16x8*)(kgb + (size_t)(t + 1) * 64 * QKVW);
      vvec = *(const u16x8*)(vgb + (size_t)(t + 1) * 64 * QKVW);
    }

    // S^T = K * Q^T (log2 units): st[tc][r] = score(key=tc*16+g*4+r, query=li)
    f32x4 st[4];
    __builtin_amdgcn_s_setprio(1);
#pragma unroll
    for (int tc = 0; tc < 4; ++tc) {
      st[tc] = f32x4{0.f, 0.f, 0.f, 0.f};
#pragma unroll
      for (int kk = 0; kk < 2; ++kk) {
        bf16x8 kf = *(const bf16x8*)&K_lds[cur][(tc * 16 + li) * 64 + ((kk * 32 + g * 8) ^ sw)];
        st[tc] = __builtin_amdgcn_mfma_f32_16x16x32_bf16(kf, qf[kk], st[tc], 0, 0, 0);
      }
    }
    __builtin_amdgcn_s_setprio(0);

    // per-query max over this tile's 64 keys
    float tm = fmaxf(fmaxf(st[0][0], st[0][1]), fmaxf(st[0][2], st[0][3]));
#pragma unroll
    for (int tc = 1; tc < 4; ++tc)
      tm = fmaxf(tm, fmaxf(fmaxf(st[tc][0], st[tc][1]), fmaxf(st[tc][2], st[tc][3])));
    tm = fmaxf(tm, __shfl_xor(tm, 16));
    tm = fmaxf(tm, __shfl_xor(tm, 32));

    // defer-max: only rescale when the running max grew by >8 (log2 units)
    if (!__all(tm - m <= 8.f)) {
      float mnew = fmaxf(m, tm);
      float corr = exp2f(m - mnew);
      l *= corr;
      float cr[4];
#pragma unroll
      for (int r = 0; r < 4; ++r) cr[r] = __shfl(corr, g * 4 + r);
#pragma unroll
      for (int nt = 0; nt < 4; ++nt)
#pragma unroll
        for (int r = 0; r < 4; ++r) oacc[nt][r] *= cr[r];
      m = mnew;
    }

    float rs = 0.f;
#pragma unroll
    for (int tc = 0; tc < 4; ++tc) {
      float p0 = exp2f(st[tc][0] - m);
      float p1 = exp2f(st[tc][1] - m);
      float p2 = exp2f(st[tc][2] - m);
      float p3 = exp2f(st[tc][3] - m);
      rs += (p0 + p1) + (p2 + p3);
      u32 lo, hi;
      asm("v_cvt_pk_bf16_f32 %0, %1, %2" : "=v"(lo) : "v"(p0), "v"(p1));
      asm("v_cvt_pk_bf16_f32 %0, %1, %2" : "=v"(hi) : "v"(p2), "v"(p3));
      u32x2 pw; pw[0] = lo; pw[1] = hi;
      *(u32x2*)&Pw[li * 64 + ((tc * 16 + g * 4) ^ sw)] = pw;  // 8B aligned (sw flips bits>=3)
    }
    rs += __shfl_xor(rs, 16);
    rs += __shfl_xor(rs, 32);
    l += rs;

    asm volatile("s_waitcnt lgkmcnt(0)" ::: "memory");  // P writes visible to wave

    __builtin_amdgcn_s_setprio(1);
#pragma unroll
    for (int kk = 0; kk < 2; ++kk) {
      bf16x8 pf = *(const bf16x8*)&Pw[li * 64 + ((kk * 32 + g * 8) ^ sw)];
#pragma unroll
      for (int nt = 0; nt < 4; ++nt) {
        bf16x8 vf = *(const bf16x8*)&Vt_lds[cur][(nt * 16 + li) * 64 + ((kk * 32 + g * 8) ^ sw)];
        oacc[nt] = __builtin_amdgcn_mfma_f32_16x16x32_bf16(pf, vf, oacc[nt], 0, 0, 0);
      }
    }
    __builtin_amdgcn_s_setprio(0);

    if (pref) {  // write next tile into the other buffer; readers of it synced below
      *(u16x8*)&K_lds[cur ^ 1][kdst] = kvec;
#pragma unroll
      for (int e = 0; e < 8; ++e)
        Vt_lds[cur ^ 1][(vd + e) * 64 + (vt ^ (((vd + e) & 7) << 3))] = vvec[e];
    }
    __syncthreads();
  }

  // epilogue
  float lr[4];
#pragma unroll
  for (int r = 0; r < 4; ++r) lr[r] = __shfl(l, g * 4 + r);
#pragma unroll
  for (int nt = 0; nt < 4; ++nt)
#pragma unroll
    for (int r = 0; r < 4; ++r) {
      int s = s0 + rg * 16 + g * 4 + r;
      int d = nt * 16 + li;
      O[(size_t)(b * S_ + s) * HID + hq * HD_ + d] = f2b(oacc[nt][r] / lr[r]);
    }
}

// ---------------- launch ----------------
extern "C" void kernel_launch(void* const* d_in, const int* in_sizes, int n_in,
                              void* d_out, int out_size, void* d_ws, size_t ws_size,
                              hipStream_t stream) {
  (void)in_sizes; (void)n_in; (void)out_size; (void)ws_size;
  const float* x  = (const float*)d_in[0];
  const float* Wq = (const float*)d_in[1];
  const float* Wk = (const float*)d_in[2];
  const float* Wv = (const float*)d_in[3];
  const float* Wo = (const float*)d_in[4];
  float* out = (float*)d_out;

  const size_t M = (size_t)B_ * S_;  // 4096
  u16* xb    = (u16*)d_ws;                        // M x 1024
  u16* WqkvT = xb    + M * DIN;                   // 1536 x 1024
  u16* WoT   = WqkvT + (size_t)QKVW * DIN;        // 1024 x 1024
  u16* QKV   = WoT   + (size_t)HID * HID;         // M x 1536
  u16* Ob    = QKV   + M * QKVW;                  // M x 1024

  k_cvt<<<dim3((int)(M * DIN / 8 / 256)), 256, 0, stream>>>(x, xb, (int)(M * DIN / 8));
  k_cvt_t<<<dim3(DIN / 32, HID / 32),       256, 0, stream>>>(Wq, WqkvT,                      DIN, HID);
  k_cvt_t<<<dim3(DIN / 32, (NKV*HD_) / 32), 256, 0, stream>>>(Wk, WqkvT + (size_t)HID * DIN,  DIN, NKV * HD_);
  k_cvt_t<<<dim3(DIN / 32, (NKV*HD_) / 32), 256, 0, stream>>>(Wv, WqkvT + (size_t)(HID + NKV*HD_) * DIN, DIN, NKV * HD_);
  k_cvt_t<<<dim3(HID / 32, HID / 32),       256, 0, stream>>>(Wo, WoT, HID, HID);

  // fused QKV projection; Q columns pre-scaled by 0.125*log2(e)
  k_gemm_bt<u16><<<dim3(QKVW / 128, (int)(M / 128)), 256, 0, stream>>>(
      xb, WqkvT, QKV, (int)M, QKVW, DIN, HID, QSCL);

  k_attn<<<dim3(S_ / 32, NKV, B_), 512, 0, stream>>>(QKV, Ob);

  k_gemm_bt<float><<<dim3(HID / 128, (int)(M / 128)), 256, 0, stream>>>(
      Ob, WoT, out, (int)M, HID, HID, 0, 1.0f);
}

// Round 5
// 134.941 us; speedup vs baseline: 2.5037x; 1.0094x over previous
//
#include <hip/hip_runtime.h>

using u16 = unsigned short;
using u32 = unsigned int;
typedef __bf16 bf16x8 __attribute__((ext_vector_type(8)));
typedef u16 u16x8 __attribute__((ext_vector_type(8)));
typedef u32 u32x2 __attribute__((ext_vector_type(2)));
typedef u32 u32x4 __attribute__((ext_vector_type(4)));
typedef float f32x4 __attribute__((ext_vector_type(4)));
typedef float f32x16 __attribute__((ext_vector_type(16)));

#define B_   2
#define S_   2048
#define DIN  1024
#define HID  1024
#define NH   16
#define NKV  4
#define HD_  64
#define QKVW 1536
// 0.125 * log2(e): folded into Q so softmax runs in exp2 domain
#define QSCL 0.1803368801111244f

__device__ __forceinline__ u16 f2b(float f) {
  u32 u = __builtin_bit_cast(u32, f);
  u32 r = (u + 0x7FFFu + ((u >> 16) & 1u)) >> 16;
  return (u16)r;
}

// async global->LDS, 16B per lane; dst is wave-uniform base + lane*16
__device__ __forceinline__ void gl16(const void* g, void* l) {
  __builtin_amdgcn_global_load_lds(
      (const __attribute__((address_space(1))) void*)g,
      (__attribute__((address_space(3))) void*)l, 16, 0, 0);
}

// ---------------- converters ----------------
__global__ void k_cvt(const float* __restrict__ in, u16* __restrict__ out, int n8) {
  int i = blockIdx.x * 256 + threadIdx.x;
  if (i >= n8) return;
  const float4* p = (const float4*)(in + (size_t)i * 8);
  float4 a = p[0], b = p[1];
  u16x8 o;
  o[0] = f2b(a.x); o[1] = f2b(a.y); o[2] = f2b(a.z); o[3] = f2b(a.w);
  o[4] = f2b(b.x); o[5] = f2b(b.y); o[6] = f2b(b.z); o[7] = f2b(b.w);
  *(u16x8*)(out + (size_t)i * 8) = o;
}

// W is K x N row-major (in,out). WT[n][k] = bf16(W[k][n]). LDS 32x32 tile transpose.
__global__ __launch_bounds__(256) void k_cvt_t(const float* __restrict__ W, u16* __restrict__ WT, int K, int N) {
  __shared__ float t[32][33];
  const int k0 = blockIdx.x * 32, n0 = blockIdx.y * 32;
  const int c = threadIdx.x & 31, r8 = threadIdx.x >> 5;
#pragma unroll
  for (int i = 0; i < 4; ++i)
    t[r8 + i * 8][c] = W[(size_t)(k0 + r8 + i * 8) * N + n0 + c];
  __syncthreads();
#pragma unroll
  for (int i = 0; i < 4; ++i)
    WT[(size_t)(n0 + r8 + i * 8) * K + k0 + c] = f2b(t[c][r8 + i * 8]);
}

// ---------------- GEMM: C = A * Bt^T (global_load_lds staging) ----------------
template <typename OutT>
__global__ __launch_bounds__(256) void k_gemm_bt(
    const u16* __restrict__ A, const u16* __restrict__ Bt,
    OutT* __restrict__ C, int M, int N, int K, int scaleCols, float scl)
{
  __shared__ u16 lA[128 * 32];
  __shared__ u16 lB[128 * 32];
  const int tid  = threadIdx.x;
  const int lane = tid & 63;
  const int wave = tid >> 6;
  const int wm = wave >> 1, wn = wave & 1;
  const int g = lane >> 4, li = lane & 15;
  const int bm = blockIdx.y * 128, bn = blockIdx.x * 128;
  const int srow = wave * 16 + (lane >> 2);
  const int scol = (lane & 3) * 8;

  f32x4 acc[4][4];
#pragma unroll
  for (int i = 0; i < 4; ++i)
#pragma unroll
    for (int j = 0; j < 4; ++j) acc[i][j] = f32x4{0.f, 0.f, 0.f, 0.f};

  const u16* Ab = A + (size_t)bm * K;
  const u16* Bb = Bt + (size_t)bn * K;

  for (int k0 = 0; k0 < K; k0 += 32) {
    __syncthreads();
#pragma unroll
    for (int h = 0; h < 2; ++h) {
      gl16(&Ab[(size_t)(h * 64 + srow) * K + k0 + scol], (char*)lA + h * 4096 + wave * 1024);
      gl16(&Bb[(size_t)(h * 64 + srow) * K + k0 + scol], (char*)lB + h * 4096 + wave * 1024);
    }
    __syncthreads();
    bf16x8 af[4], bfr[4];
#pragma unroll
    for (int mt = 0; mt < 4; ++mt)
      af[mt] = *(const bf16x8*)&lA[(wm * 64 + mt * 16 + li) * 32 + g * 8];
#pragma unroll
    for (int nt = 0; nt < 4; ++nt)
      bfr[nt] = *(const bf16x8*)&lB[(wn * 64 + nt * 16 + li) * 32 + g * 8];
    __builtin_amdgcn_s_setprio(1);
#pragma unroll
    for (int mt = 0; mt < 4; ++mt)
#pragma unroll
      for (int nt = 0; nt < 4; ++nt)
        acc[mt][nt] = __builtin_amdgcn_mfma_f32_16x16x32_bf16(af[mt], bfr[nt], acc[mt][nt], 0, 0, 0);
    __builtin_amdgcn_s_setprio(0);
  }

#pragma unroll
  for (int mt = 0; mt < 4; ++mt)
#pragma unroll
    for (int nt = 0; nt < 4; ++nt)
#pragma unroll
      for (int r = 0; r < 4; ++r) {
        int row = bm + wm * 64 + mt * 16 + g * 4 + r;
        int col = bn + wn * 64 + nt * 16 + li;
        float v = acc[mt][nt][r];
        if (col < scaleCols) v *= scl;
        if constexpr (sizeof(OutT) == 4) C[(size_t)row * N + col] = v;
        else                             C[(size_t)row * N + col] = f2b(v);
      }
}

// ---------------- flash attention: 8 waves, 32x32 MFMA, in-register P ----------------
// Swapped QK^T (S^T = K*Q^T), softmax fully in-register, P redistributed to the
// PV A-fragment via cvt_pk + permlane32_swap (no P LDS round-trip).
// Block: 8 waves = 4 heads x 2 q-blocks of 32 rows; K/V tiles (64 keys) staged
// once per block, double-buffered, XOR-swizzled. grid (S/64, NKV, B), block 512.
__global__ __launch_bounds__(512, 2) void k_attn(
    const u16* __restrict__ QKV, u16* __restrict__ O)
{
  __shared__ u16 K_lds[2][64 * 64];
  __shared__ u16 Vt_lds[2][64 * 64];
  const int tid  = threadIdx.x;
  const int lane = tid & 63;
  const int w    = tid >> 6;
  const int lq = lane & 31;        // query (softmax/PV-A) / key-row (QK-A) / d-row (PV-B)
  const int hi = lane >> 5;
  const int swl = (lq & 7) << 3;   // row-XOR swizzle term (row&7 == lq&7 for row = 32k+lq)
  const int hx = (hi * 8) ^ (swl & 8);
  const int s0 = blockIdx.x * 64;
  const int kv = blockIdx.y;
  const int b  = blockIdx.z;
  const int hq = kv * 4 + (w & 3);
  const int wq = w >> 2;           // which 32-row q-block

  int dcol[4];
#pragma unroll
  for (int d0 = 0; d0 < 4; ++d0) dcol[d0] = (d0 * 16) ^ (swl & 48);

  // Q fragments: B-operand of 32x32x16. qf[d0]: Q[s0+wq*32+lq][hq*64 + d0*16 + hi*8 ..+7]
  bf16x8 qf[4];
  {
    const u16* qb = QKV + (size_t)(b * S_ + s0 + wq * 32 + lq) * QKVW + hq * HD_ + hi * 8;
#pragma unroll
    for (int d0 = 0; d0 < 4; ++d0) qf[d0] = *(const bf16x8*)(qb + d0 * 16);
  }

  float m = -1e30f, l = 0.f;
  f32x16 oacc0 = {}, oacc1 = {};   // O columns dh*32 + lq, rows (reg&3)+8*(reg>>2)+4*hi

  // staging assignments (512 threads; 64x64 K tile + 64x64 V^T tile)
  const int kt = tid >> 3, kc = (tid & 7) * 8;
  const u16* kgb = QKV + (size_t)(b * S_ + kt) * QKVW + HID + kv * HD_ + kc;
  const int vt = tid & 63, vd = (tid >> 6) * 8;
  const u16* vgb = QKV + (size_t)(b * S_ + vt) * QKVW + HID + NKV * HD_ + kv * HD_ + vd;
  const int kdst = kt * 64 + (kc ^ ((kt & 7) << 3));

  // prologue: stage tile 0 into buffer 0
  {
    u16x8 kvec = *(const u16x8*)(kgb);
    u16x8 vvec = *(const u16x8*)(vgb);
    *(u16x8*)&K_lds[0][kdst] = kvec;
#pragma unroll
    for (int e = 0; e < 8; ++e)
      Vt_lds[0][(vd + e) * 64 + (vt ^ (((vd + e) & 7) << 3))] = vvec[e];
  }
  __syncthreads();

  constexpr int NT = S_ / 64;
  for (int t = 0; t < NT; ++t) {
    const int cur = t & 1;
    u16x8 kvec, vvec;
    const bool pref = (t + 1 < NT);
    if (pref) {
      kvec = *(const u16x8*)(kgb + (size_t)(t + 1) * 64 * QKVW);
      vvec = *(const u16x8*)(vgb + (size_t)(t + 1) * 64 * QKVW);
    }

    // S^T = K * Q^T (log2 units). st0: keys 0-31, st1: keys 32-63 of this tile.
    // Lane (q=lq, hi) holds keys (reg&3)+8*(reg>>2)+4*hi per half.
    f32x16 st0 = {}, st1 = {};
    __builtin_amdgcn_s_setprio(1);
#pragma unroll
    for (int d0 = 0; d0 < 4; ++d0) {
      bf16x8 kf0 = *(const bf16x8*)&K_lds[cur][lq * 64 + dcol[d0] + hx];
      bf16x8 kf1 = *(const bf16x8*)&K_lds[cur][(32 + lq) * 64 + dcol[d0] + hx];
      st0 = __builtin_amdgcn_mfma_f32_32x32x16_bf16(kf0, qf[d0], st0, 0, 0, 0);
      st1 = __builtin_amdgcn_mfma_f32_32x32x16_bf16(kf1, qf[d0], st1, 0, 0, 0);
    }
    __builtin_amdgcn_s_setprio(0);

    // per-query tile max (31 fmax + 1 cross-half combine)
    float tm = st0[0];
#pragma unroll
    for (int i = 1; i < 16; ++i) tm = fmaxf(tm, st0[i]);
#pragma unroll
    for (int i = 0; i < 16; ++i) tm = fmaxf(tm, st1[i]);
    tm = fmaxf(tm, __shfl_xor(tm, 32));

    // defer-max: rescale only when the running max grew by >8 (log2 units)
    if (!__all(tm - m <= 8.f)) {
      float mnew = fmaxf(m, tm);
      float corr = exp2f(m - mnew);
      l *= corr;
#pragma unroll
      for (int r = 0; r < 16; ++r) {
        float cq = __shfl(corr, (r & 3) + 8 * (r >> 2) + 4 * hi);
        oacc0[r] *= cq;
        oacc1[r] *= cq;
      }
      m = mnew;
    }

    // exp + row-sum (in-register)
    float rs = 0.f;
    f32x16 e0, e1;
#pragma unroll
    for (int i = 0; i < 16; ++i) { e0[i] = exp2f(st0[i] - m); rs += e0[i]; }
#pragma unroll
    for (int i = 0; i < 16; ++i) { e1[i] = exp2f(st1[i] - m); rs += e1[i]; }
    rs += __shfl_xor(rs, 32);
    l += rs;

    // P -> PV A-fragments in registers: pa[ks] covers keys ks*16 + hi*8 + j.
    // swap(pk(p0,p1), pk(p4,p5)) -> (word j=0, word j=2); q preserved per lane.
    bf16x8 pa[4];
#define PK(dst, x, y) asm("v_cvt_pk_bf16_f32 %0, %1, %2" : "=v"(dst) : "v"(x), "v"(y))
#pragma unroll
    for (int kb = 0; kb < 2; ++kb) {
      const f32x16& ev = kb ? e1 : e0;
      u32 a0, a1, b0, b1;
      u32x2 r0, r1;
      u32x4 wv;
      PK(a0, ev[0], ev[1]);  PK(a1, ev[2], ev[3]);
      PK(b0, ev[4], ev[5]);  PK(b1, ev[6], ev[7]);
      r0 = __builtin_amdgcn_permlane32_swap(a0, b0, false, false);
      r1 = __builtin_amdgcn_permlane32_swap(a1, b1, false, false);
      wv[0] = r0[0]; wv[1] = r1[0]; wv[2] = r0[1]; wv[3] = r1[1];
      pa[kb * 2] = __builtin_bit_cast(bf16x8, wv);
      PK(a0, ev[8],  ev[9]);  PK(a1, ev[10], ev[11]);
      PK(b0, ev[12], ev[13]); PK(b1, ev[14], ev[15]);
      r0 = __builtin_amdgcn_permlane32_swap(a0, b0, false, false);
      r1 = __builtin_amdgcn_permlane32_swap(a1, b1, false, false);
      wv[0] = r0[0]; wv[1] = r1[0]; wv[2] = r0[1]; wv[3] = r1[1];
      pa[kb * 2 + 1] = __builtin_bit_cast(bf16x8, wv);
    }
#undef PK

    // O += P(32q x 64k) * V(64k x 64d)
    __builtin_amdgcn_s_setprio(1);
#pragma unroll
    for (int ks = 0; ks < 4; ++ks) {
      bf16x8 vf0 = *(const bf16x8*)&Vt_lds[cur][lq * 64 + dcol[ks] + hx];
      bf16x8 vf1 = *(const bf16x8*)&Vt_lds[cur][(32 + lq) * 64 + dcol[ks] + hx];
      oacc0 = __builtin_amdgcn_mfma_f32_32x32x16_bf16(pa[ks], vf0, oacc0, 0, 0, 0);
      oacc1 = __builtin_amdgcn_mfma_f32_32x32x16_bf16(pa[ks], vf1, oacc1, 0, 0, 0);
    }
    __builtin_amdgcn_s_setprio(0);

    if (pref) {
      *(u16x8*)&K_lds[cur ^ 1][kdst] = kvec;
#pragma unroll
      for (int e = 0; e < 8; ++e)
        Vt_lds[cur ^ 1][(vd + e) * 64 + (vt ^ (((vd + e) & 7) << 3))] = vvec[e];
    }
    __syncthreads();
  }

  // epilogue: O[s][hq*64 + dh*32 + lq], rows from C-layout
  const size_t obase = (size_t)(b * S_ + s0 + wq * 32) * HID + hq * HD_ + lq;
#pragma unroll
  for (int r = 0; r < 16; ++r) {
    const int qrow = (r & 3) + 8 * (r >> 2) + 4 * hi;
    float lr = __shfl(l, qrow);
    float inv = __builtin_amdgcn_rcpf(lr);
    O[obase + (size_t)qrow * HID]      = f2b(oacc0[r] * inv);
    O[obase + (size_t)qrow * HID + 32] = f2b(oacc1[r] * inv);
  }
}

// ---------------- launch ----------------
extern "C" void kernel_launch(void* const* d_in, const int* in_sizes, int n_in,
                              void* d_out, int out_size, void* d_ws, size_t ws_size,
                              hipStream_t stream) {
  (void)in_sizes; (void)n_in; (void)out_size; (void)ws_size;
  const float* x  = (const float*)d_in[0];
  const float* Wq = (const float*)d_in[1];
  const float* Wk = (const float*)d_in[2];
  const float* Wv = (const float*)d_in[3];
  const float* Wo = (const float*)d_in[4];
  float* out = (float*)d_out;

  const size_t M = (size_t)B_ * S_;  // 4096
  u16* xb    = (u16*)d_ws;                        // M x 1024
  u16* WqkvT = xb    + M * DIN;                   // 1536 x 1024
  u16* WoT   = WqkvT + (size_t)QKVW * DIN;        // 1024 x 1024
  u16* QKV   = WoT   + (size_t)HID * HID;         // M x 1536
  u16* Ob    = QKV   + M * QKVW;                  // M x 1024

  k_cvt<<<dim3((int)(M * DIN / 8 / 256)), 256, 0, stream>>>(x, xb, (int)(M * DIN / 8));
  k_cvt_t<<<dim3(DIN / 32, HID / 32),       256, 0, stream>>>(Wq, WqkvT,                      DIN, HID);
  k_cvt_t<<<dim3(DIN / 32, (NKV*HD_) / 32), 256, 0, stream>>>(Wk, WqkvT + (size_t)HID * DIN,  DIN, NKV * HD_);
  k_cvt_t<<<dim3(DIN / 32, (NKV*HD_) / 32), 256, 0, stream>>>(Wv, WqkvT + (size_t)(HID + NKV*HD_) * DIN, DIN, NKV * HD_);
  k_cvt_t<<<dim3(HID / 32, HID / 32),       256, 0, stream>>>(Wo, WoT, HID, HID);

  // fused QKV projection; Q columns pre-scaled by 0.125*log2(e)
  k_gemm_bt<u16><<<dim3(QKVW / 128, (int)(M / 128)), 256, 0, stream>>>(
      xb, WqkvT, QKV, (int)M, QKVW, DIN, HID, QSCL);

  k_attn<<<dim3(S_ / 64, NKV, B_), 512, 0, stream>>>(QKV, Ob);

  k_gemm_bt<float><<<dim3(HID / 128, (int)(M / 128)), 256, 0, stream>>>(
      Ob, WoT, out, (int)M, HID, HID, 0, 1.0f);
}